// Round 6
// baseline (6862.733 us; speedup 1.0000x reference)
//
#include <hip/hip_runtime.h>
#include <hip/hip_bf16.h>

// ShiftReduceCompressor: persistent kernel, 1 block/row (B=64), 1024 threads,
// 32-iteration scan in-kernel. Encoder fp32, sampling tail fp64, exact
// partitionable JAX threefry. Weights staged bf16->f32 AND TRANSPOSED
// (k-major) into d_ws so weight reads are lane-coalesced.

#define XS 132
#define QS 388
#define HS 516
#define PS 36
#define NW 16

// ======================= common helpers =======================
__device__ __forceinline__ float ldw(const float* p){ return *p; }
__device__ __forceinline__ float ldw(const unsigned short* p){
  return __uint_as_float(((unsigned)*p) << 16);
}
__device__ __forceinline__ float4 ld4(const float* p){ return *(const float4*)p; }
__device__ __forceinline__ float4 ld4(const unsigned short* p){
  ushort4 u = *(const ushort4*)p;
  return make_float4(__uint_as_float((unsigned)u.x << 16),
                     __uint_as_float((unsigned)u.y << 16),
                     __uint_as_float((unsigned)u.z << 16),
                     __uint_as_float((unsigned)u.w << 16));
}
template<typename WT>
__device__ __forceinline__ double ldwd(const WT* p){ return (double)ldw(p); }

__device__ __forceinline__ float temb(const void* te, int isb, long long idx){
  if (isb) return __uint_as_float(((unsigned)((const unsigned short*)te)[idx]) << 16);
  return ((const float*)te)[idx];
}

__device__ __forceinline__ void tfry(unsigned k0, unsigned k1, unsigned x0, unsigned x1,
                                     unsigned &o0, unsigned &o1){
  unsigned ks2 = k0 ^ k1 ^ 0x1BD11BDAu;
  unsigned x = x0 + k0, y = x1 + k1;
#define TFR(r) { x += y; y = (y << r) | (y >> (32 - r)); y ^= x; }
  TFR(13) TFR(15) TFR(26) TFR(6)  x += k1;  y += ks2 + 1u;
  TFR(17) TFR(29) TFR(16) TFR(24) x += ks2; y += k0 + 2u;
  TFR(13) TFR(15) TFR(26) TFR(6)  x += k0;  y += k1 + 3u;
  TFR(17) TFR(29) TFR(16) TFR(24) x += k1;  y += ks2 + 4u;
  TFR(13) TFR(15) TFR(26) TFR(6)  x += ks2; y += k0 + 5u;
#undef TFR
  o0 = x; o1 = y;
}
__device__ __forceinline__ float u01(unsigned bits){
  return __uint_as_float((bits >> 9) | 0x3f800000u) - 1.0f;
}
__device__ __forceinline__ double logsigd(double x){
  return fmin(x, 0.0) - log1p(exp(-fabs(x)));
}
__device__ __forceinline__ float wredsum(float v, int width){
  for (int m = width >> 1; m > 0; m >>= 1) v += __shfl_xor(v, m, width);
  return v;
}
__device__ __forceinline__ double wredsumd(double v, int width){
  for (int m = width >> 1; m > 0; m >>= 1) v += __shfl_xor(v, m, width);
  return v;
}
__device__ __forceinline__ float dot4f(float4 a, float4 b){
  return a.x*b.x + a.y*b.y + a.z*b.z + a.w*b.w;
}

struct Smem {
  float xbuf[32 * XS];
  float qh[32 * HS];
  float obuf[32 * XS];
  float pbuf[4608];
  float attT[128];
  float tva[128];
  double gild[384];
  double ghld[384];
  double hsd[128];
  double t1d[64];
  double catd[320];
  double hid2d[384];
  double logitsd[3];
  int win_ids[32];
  int sI[6];
  unsigned keyts[32][2];
};

// ======================= transposed-weight path =======================
struct TParams {
  const int* token_ids;
  const unsigned char* pad;
  const void* tok_emb;
  const int* flag;    // emb-is-bf16
  const float *pos_emb, *WqkvT0, *WqkvT1, *bqkv, *WoT0, *WoT1, *bo, *ln1g, *ln1b;
  const float *W1T0, *W1T1, *b1, *W2T0, *W2T1, *b2, *ln2g, *ln2b;
  const float *projWT, *projb, *gWihT, *gWhhT, *gbih, *gbhh;
  const float *accW1T, *accb1, *accW2, *accb2;
  const float *emtW1T, *emtb1, *emtW2, *emtb2;
  const float *evtW1T, *evtb1, *evtW2, *evtb2;
  float* out;
};

// out[tok][j] = bias[j] + sum_k WT[k*jstr + j] * x[tok][k]; lane covers 2 j.
template<int T, bool RELU>
__device__ void gemm_t(const float* __restrict__ WT, int jstr,
                       const float* __restrict__ bias, int J, int K,
                       const float* __restrict__ xl, int xs,
                       float* __restrict__ ol, int os, int ntok,
                       int lane, int wv, int nwv)
{
  const int JG = J >> 7;
  const int ntt = (ntok + T - 1) / T;
  for (int item = wv; item < JG * ntt; item += nwv) {
    const int jg = item % JG, tt = item / JG;
    const int j0 = jg * 128 + lane * 2;
    float ax[T], ay[T];
#pragma unroll
    for (int t = 0; t < T; ++t) { ax[t] = 0.f; ay[t] = 0.f; }
    const float* xr = xl + tt * T * xs;
    const float* wp = WT + j0;
#pragma unroll 2
    for (int k = 0; k < K; k += 4) {
      float4 xv[T];
#pragma unroll
      for (int t = 0; t < T; ++t) xv[t] = *(const float4*)(xr + t * xs + k);
      float2 w0 = *(const float2*)(wp + (k + 0) * jstr);
      float2 w1 = *(const float2*)(wp + (k + 1) * jstr);
      float2 w2 = *(const float2*)(wp + (k + 2) * jstr);
      float2 w3 = *(const float2*)(wp + (k + 3) * jstr);
#pragma unroll
      for (int t = 0; t < T; ++t) {
        ax[t] += w0.x * xv[t].x; ay[t] += w0.y * xv[t].x;
        ax[t] += w1.x * xv[t].y; ay[t] += w1.y * xv[t].y;
        ax[t] += w2.x * xv[t].z; ay[t] += w2.y * xv[t].z;
        ax[t] += w3.x * xv[t].w; ay[t] += w3.y * xv[t].w;
      }
    }
    float bx = bias[j0], by = bias[j0 + 1];
#pragma unroll
    for (int t = 0; t < T; ++t) {
      int tok = tt * T + t;
      if (tok < ntok) {
        float vx = ax[t] + bx, vy = ay[t] + by;
        if (RELU) { vx = fmaxf(vx, 0.f); vy = fmaxf(vy, 0.f); }
        *(float2*)(ol + tok * os + j0) = make_float2(vx, vy);
      }
    }
  }
}

__device__ __forceinline__ float dott_f(const float* __restrict__ WT, int jstr, int j,
                                        const float* __restrict__ x, int K){
  float acc = 0.f;
#pragma unroll 8
  for (int k = 0; k < K; ++k) acc += WT[k * jstr + j] * x[k];
  return acc;
}
__device__ __forceinline__ double dott_d(const float* __restrict__ WT, int jstr, int j,
                                         const double* __restrict__ x, int K){
  double acc = 0.0;
#pragma unroll 4
  for (int k = 0; k < K; ++k) acc += (double)WT[k * jstr + j] * x[k];
  return acc;
}
__device__ __forceinline__ double dott_dx(const float* __restrict__ WT, int jstr, int j,
                                          const float* __restrict__ x, int K){
  double acc = 0.0;
#pragma unroll 4
  for (int k = 0; k < K; ++k) acc += (double)WT[k * jstr + j] * (double)x[k];
  return acc;
}

// post-norm LN over D=128 for rows <W (threads 0..255)
__device__ void ln_rowsF(float* xb, const float* ob, const float* __restrict__ g,
                         const float* __restrict__ bb, int W, int tid){
  if (tid >= 256) return;
  const int i = tid >> 3, sub = tid & 7;
  const int base = i * XS + sub * 16;
  float y[16];
  float s = 0.f;
#pragma unroll
  for (int u = 0; u < 16; ++u) { y[u] = xb[base + u] + ob[base + u]; s += y[u]; }
  s = wredsum(s, 8);
  const float m = s * (1.0f / 128.0f);
  float vs = 0.f;
#pragma unroll
  for (int u = 0; u < 16; ++u) { float d = y[u] - m; vs += d * d; }
  vs = wredsum(vs, 8);
  const float rstd = 1.0f / sqrtf(vs * (1.0f / 128.0f) + 1e-5f);
  if (i < W) {
#pragma unroll
    for (int u = 0; u < 16; ++u)
      xb[base + u] = (y[u] - m) * rstd * g[sub * 16 + u] + bb[sub * 16 + u];
  }
}
__device__ __forceinline__ void ln_tailF(float* xrow, const float* add,
                                         const float* __restrict__ g,
                                         const float* __restrict__ bb, int tid){
  if (tid < 64) {
    float y0 = xrow[tid] + add[tid];
    float y1 = xrow[64 + tid] + add[64 + tid];
    float m = wredsum(y0 + y1, 64) * (1.0f / 128.0f);
    float d0 = y0 - m, d1 = y1 - m;
    float rstd = 1.0f / sqrtf(wredsum(d0 * d0 + d1 * d1, 64) * (1.0f / 128.0f) + 1e-5f);
    xrow[tid] = d0 * rstd * g[tid] + bb[tid];
    xrow[64 + tid] = d1 * rstd * g[64 + tid] + bb[64 + tid];
  }
}

__global__ __launch_bounds__(1024) void src_main_t(TParams P){
  __shared__ __align__(16) Smem S;
  const int row = blockIdx.x;
  const int tid = threadIdx.x;
  const int lane = tid & 63, wid = tid >> 6;
  const int isbEmb = *P.flag;

  if (tid == 0) {
    int seq = 0;
    for (int l = 0; l < 64; ++l) seq += (P.pad[row * 64 + l] == 0);
    S.sI[0] = 0; S.sI[1] = 0; S.sI[2] = (seq == 0) ? 1 : 0; S.sI[3] = seq; S.sI[4] = 0;
  }
  if (tid < 128) S.hsd[tid] = 0.0;
  if (tid < 32) {
    S.win_ids[tid] = 0;
    unsigned a0, a1;
    tfry(0u, 42u, 0u, (unsigned)tid, a0, a1);
    S.keyts[tid][0] = a0; S.keyts[tid][1] = a1;
  }
  __syncthreads();

  for (int t = 0; t < 32; ++t) {
    const int wl = S.sI[0], ip = S.sI[1], done = S.sI[2], seq = S.sI[3];
    const int act = !done;
    const int W = wl;
    const int enc = (act && wl > 0) ? 1 : 0;
    const int jl = (W > 0) ? (W - 1) : 0;

    if (enc) {
      for (int idx = tid; idx < W * 128; idx += 1024) {
        int i = idx >> 7, d = idx & 127;
        S.xbuf[i * XS + d] = temb(P.tok_emb, isbEmb, (long long)S.win_ids[i] * 128 + d)
                             + P.pos_emb[i * 128 + d];
      }
      __syncthreads();
      // ---- layer 0 (full) ----
      gemm_t<4, false>(P.WqkvT0, 384, P.bqkv, 384, 128, S.xbuf, XS, S.qh, QS, W, lane, wid, NW);
      __syncthreads();
      if (tid < 128) {
        int h = tid >> 5, i = tid & 31;
        if (i < W) {
          float4 q[8];
#pragma unroll
          for (int kk = 0; kk < 8; ++kk) q[kk] = *(const float4*)&S.qh[i * QS + h * 32 + kk * 4];
          int pb = (h * 32 + i) * PS;
          float m = -1e30f;
          for (int j = 0; j < W; ++j) {
            float s = 0.f;
#pragma unroll
            for (int kk = 0; kk < 8; ++kk)
              s += dot4f(q[kk], *(const float4*)&S.qh[j * QS + 128 + h * 32 + kk * 4]);
            s *= 0.17677669529663687f;
            S.pbuf[pb + j] = s;
            m = fmaxf(m, s);
          }
          float sum = 0.f;
          for (int j = 0; j < W; ++j) { float e = expf(S.pbuf[pb + j] - m); S.pbuf[pb + j] = e; sum += e; }
          float rs = 1.0f / sum;
          for (int j = 0; j < W; ++j) S.pbuf[pb + j] *= rs;
        }
      }
      __syncthreads();
      {
        int c = tid & 127, qsub = tid >> 7, h = c >> 5;
        for (int i = qsub; i < W; i += 8) {
          float acc = 0.f;
          for (int j = 0; j < W; ++j) acc += S.pbuf[(h * 32 + i) * PS + j] * S.qh[j * QS + 256 + c];
          S.obuf[i * XS + c] = acc;
        }
      }
      __syncthreads();
      gemm_t<4, false>(P.WoT0, 128, P.bo, 128, 128, S.obuf, XS, S.pbuf, XS, W, lane, wid, NW);
      __syncthreads();
      ln_rowsF(S.xbuf, S.pbuf, P.ln1g, P.ln1b, W, tid);
      __syncthreads();
      gemm_t<4, true>(P.W1T0, 512, P.b1, 512, 128, S.xbuf, XS, S.qh, HS, W, lane, wid, NW);
      __syncthreads();
      gemm_t<4, false>(P.W2T0, 128, P.b2, 128, 512, S.qh, HS, S.obuf, XS, W, lane, wid, NW);
      __syncthreads();
      ln_rowsF(S.xbuf, S.obuf, P.ln2g, P.ln2b, W, tid);
      __syncthreads();
      // ---- layer 1 (last-token only): KV gemm (waves 0..13) + Q dot (waves 14,15) ----
      if (wid < 14) {
        gemm_t<4, false>(P.WqkvT1 + 128, 384, P.bqkv + 384 + 128, 256, 128,
                         S.xbuf, XS, S.qh + 128, QS, W, lane, wid, 14);
      } else {
        int j = tid - 896;  // 0..127
        S.qh[jl * QS + j] = P.bqkv[384 + j] + dott_f(P.WqkvT1, 384, j, &S.xbuf[jl * XS], 128);
      }
      __syncthreads();
      if (tid < 128) {
        int h = tid >> 5, j = tid & 31;
        float s = -1e30f;
        if (j < W) {
          s = 0.f;
#pragma unroll
          for (int kk = 0; kk < 8; ++kk)
            s += dot4f(*(const float4*)&S.qh[jl * QS + h * 32 + kk * 4],
                       *(const float4*)&S.qh[j * QS + 128 + h * 32 + kk * 4]);
          s *= 0.17677669529663687f;
        }
        float m = s;
        for (int mk = 16; mk; mk >>= 1) m = fmaxf(m, __shfl_xor(m, mk, 32));
        float e = (j < W) ? expf(s - m) : 0.f;
        float sum = e;
        for (int mk = 16; mk; mk >>= 1) sum += __shfl_xor(sum, mk, 32);
        if (j < W) S.pbuf[h * PS + j] = e * (1.0f / sum);
      }
      __syncthreads();
      if (tid < 128) {
        int h = tid >> 5;
        float acc = 0.f;
        for (int j = 0; j < W; ++j) acc += S.pbuf[h * PS + j] * S.qh[j * QS + 256 + tid];
        S.attT[tid] = acc;
      }
      __syncthreads();
      if (tid < 128)
        S.tva[tid] = P.bo[128 + tid] + dott_f(P.WoT1, 128, tid, S.attT, 128);
      __syncthreads();
      ln_tailF(&S.xbuf[jl * XS], S.tva, P.ln1g + 128, P.ln1b + 128, tid);
      __syncthreads();
      if (tid < 512)
        S.qh[tid] = fmaxf(P.b1[512 + tid] + dott_f(P.W1T1, 512, tid, &S.xbuf[jl * XS], 128), 0.f);
      __syncthreads();
      if (tid < 128)
        S.tva[tid] = P.b2[128 + tid] + dott_f(P.W2T1, 128, tid, S.qh, 512);
      __syncthreads();
      ln_tailF(&S.xbuf[jl * XS], S.tva, P.ln2g + 128, P.ln2b + 128, tid);
      __syncthreads();
    }

    // ---- stage A: proj->t1 (tid<64) | ghl (384..767) | catd-emb (768..895) ----
    if (tid < 64) {
      double tv = 0.0;
      if (enc) {
        double v = (double)P.projb[tid] + dott_dx(P.projWT, 64, tid, &S.xbuf[jl * XS], 128);
        double ss = wredsumd(v * v, 64);
        tv = v / fmax(sqrt(ss), 1e-12);
      }
      S.t1d[tid] = tv;
      S.catd[128 + tid] = tv;
      P.out[(size_t)t * 4096 + row * 64 + tid] = (float)tv;
    } else if (tid >= 384 && tid < 768) {
      if (act) {
        int j = tid - 384;
        S.ghld[j] = (double)P.gbhh[j] + dott_d(P.gWhhT, 384, j, S.hsd, 128);
      }
    } else if (tid >= 768 && tid < 896) {
      int j = tid - 768;
      int ipc = ip < 0 ? 0 : (ip > 63 ? 63 : ip);
      int nt = P.token_ids[row * 64 + ipc];
      int has_in = (act && (ip < seq)) ? 1 : 0;
      S.catd[j] = has_in ? (double)temb(P.tok_emb, isbEmb, (long long)nt * 128 + j) : 0.0;
    }
    __syncthreads();

    // ---- stage B: gil (needs t1) ----
    if (act) {
      if (tid < 384)
        S.gild[tid] = (double)P.gbih[tid] + dott_d(P.gWihT, 384, tid, S.t1d, 64);
      __syncthreads();
    }

    // ---- stage C: hsd update + catd-h ----
    if (tid < 128) {
      if (act) {
        double r = 1.0 / (1.0 + exp(-(S.gild[tid] + S.ghld[tid])));
        double z = 1.0 / (1.0 + exp(-(S.gild[128 + tid] + S.ghld[128 + tid])));
        double n = tanh(S.gild[256 + tid] + r * S.ghld[256 + tid]);
        S.hsd[tid] = (1.0 - z) * n + z * S.hsd[tid];
      }
      S.catd[192 + tid] = S.hsd[tid];
    }
    __syncthreads();

    // ---- stage D: three head hidden layers ----
    if (tid < 128) {
      S.hid2d[tid] = fmax((double)P.accb1[tid] + dott_d(P.accW1T, 128, tid, S.catd, 320), 0.0);
    } else if (tid < 256) {
      int j = tid - 128;
      S.hid2d[128 + j] = fmax((double)P.emtb1[j] + dott_d(P.emtW1T, 128, j, S.catd + 128, 192), 0.0);
    } else if (tid < 384) {
      int j = tid - 256;
      S.hid2d[256 + j] = fmax((double)P.evtb1[j] + dott_d(P.evtW1T, 128, j, S.catd + 128, 192), 0.0);
    }
    __syncthreads();

    // ---- stage E: three logits ----
    {
      int hw = tid >> 6;
      if (hw < 3) {
        int ln = tid & 63;
        const float* w2 = (hw == 0) ? P.accW2 : ((hw == 1) ? P.emtW2 : P.evtW2);
        const float* b2p = (hw == 0) ? P.accb2 : ((hw == 1) ? P.emtb2 : P.evtb2);
        double pp = S.hid2d[hw * 128 + ln] * (double)w2[ln]
                  + S.hid2d[hw * 128 + 64 + ln] * (double)w2[64 + ln];
        pp = wredsumd(pp, 64);
        if (ln == 0) S.logitsd[hw] = pp + (double)b2p[0];
      }
    }
    __syncthreads();

    // ---- stage F: sample + state update ----
    if (tid == 0) {
      unsigned k0 = S.keyts[t][0], k1 = S.keyts[t][1];
      unsigned sk[3][2];
      tfry(k0, k1, 0u, 0u, sk[0][0], sk[0][1]);
      tfry(k0, k1, 0u, 1u, sk[1][0], sk[1][1]);
      tfry(k0, k1, 0u, 2u, sk[2][0], sk[2][1]);
      int smp[3];
      double lg[3] = {S.logitsd[0], S.logitsd[1], S.logitsd[2]};
      for (int s = 0; s < 3; ++s) {
        unsigned r0, r1;
        tfry(sk[s][0], sk[s][1], 0u, (unsigned)row, r0, r1);
        unsigned bits = r0 ^ r1;
        double u = (double)u01(bits);
        double p = 1.0 / (1.0 + exp(-lg[s]));
        smp[s] = (u < p) ? 1 : 0;
        P.out[131072 + (size_t)t * 192 + row * 3 + s] = (float)logsigd(smp[s] ? lg[s] : -lg[s]);
        P.out[137216 + (size_t)t * 192 + row * 3 + s] = smp[s] ? 1.0f : 0.0f;
      }
      int wl2 = wl, ip2 = ip, dn = done;
      int nonempty = (wl2 > 0) && act;
      int has_in = act && (ip2 < seq);
      int a = smp[0] && has_in;
      int e = smp[1] && nonempty;
      int v = smp[2] && nonempty;
      int none = act && !(a || e || v);
      a = a || (none && has_in);
      e = e || (none && !has_in && (wl2 > 0));
      int aeff = a && (wl2 < 32);
      int ipc = ip2 < 0 ? 0 : (ip2 > 63 ? 63 : ip2);
      int nt = P.token_ids[row * 64 + ipc];
      if (aeff) { S.win_ids[wl2] = nt; ip2 += 1; wl2 += 1; }
      int emit = e && (wl2 > 0);
      S.sI[4] += emit;
      int veff = v && (wl2 > 0);
      if (veff) {
        int w0 = S.win_ids[0];
#pragma unroll
        for (int i2 = 0; i2 < 31; ++i2) S.win_ids[i2] = S.win_ids[i2 + 1];
        S.win_ids[31] = w0;
        wl2 -= 1;
      }
      if (act && (ip2 >= seq) && (wl2 == 0)) dn = 1;
      S.sI[0] = wl2; S.sI[1] = ip2; S.sI[2] = dn;
    }
    __syncthreads();
  }
  if (tid == 0) P.out[143360 + row] = (float)S.sI[4];
}

// ======================= staging (convert + transpose) =======================
struct TEnt { const void* src; int srcOff; int J; int K; int trans; int off; };
struct CvtT { TEnt e[35]; float* dst; int* flag; const unsigned short* probe; };

__global__ __launch_bounds__(256) void cvt_t_kernel(CvtT C){
  const bool isb = (C.probe[0] == (unsigned short)0x3F80);
  if (blockIdx.x == 0 && threadIdx.x == 0) *C.flag = isb ? 1 : 0;
  const int gid = blockIdx.x * 256 + threadIdx.x;
  const int gstr = gridDim.x * 256;
  for (int e = 0; e < 35; ++e) {
    const int J = C.e[e].J, K = C.e[e].K, n = J * K;
    float* d = C.dst + C.e[e].off;
    if (C.e[e].trans) {
      if (isb) {
        const unsigned short* s = (const unsigned short*)C.e[e].src + C.e[e].srcOff;
        for (int i = gid; i < n; i += gstr) {
          int k = i / J, j = i - k * J;
          d[i] = __uint_as_float(((unsigned)s[j * K + k]) << 16);
        }
      } else {
        const float* s = (const float*)C.e[e].src + C.e[e].srcOff;
        for (int i = gid; i < n; i += gstr) {
          int k = i / J, j = i - k * J;
          d[i] = s[j * K + k];
        }
      }
    } else {
      if (isb) {
        const unsigned short* s = (const unsigned short*)C.e[e].src + C.e[e].srcOff;
        for (int i = gid; i < n; i += gstr) d[i] = __uint_as_float(((unsigned)s[i]) << 16);
      } else {
        const float* s = (const float*)C.e[e].src + C.e[e].srcOff;
        for (int i = gid; i < n; i += gstr) d[i] = s[i];
      }
    }
  }
}

// ======================= fallback (round-5 direct path) =======================
struct KParams {
  const int* token_ids;
  const unsigned char* pad;
  const void *tok_emb, *pos_emb, *Wqkv, *bqkv, *Wo, *bo, *ln1g, *ln1b;
  const void *W1, *b1, *W2, *b2, *ln2g, *ln2b, *projW, *projb;
  const void *gWih, *gWhh, *gbih, *gbhh;
  const void *accW1, *accb1, *accW2, *accb2;
  const void *emtW1, *emtb1, *emtW2, *emtb2;
  const void *evtW1, *evtb1, *evtW2, *evtb2;
  float* out;
};

template<int J2, int T, int K, bool RELU, typename WT>
__device__ void gemm_tok(const WT* __restrict__ Wm, const WT* __restrict__ bias,
                         int J, const float* __restrict__ xl, int xs,
                         float* __restrict__ ol, int os, int ntok, int tid)
{
  const int lane = tid & 63, wid = tid >> 6;
  const int JBG = J / (64 * J2);
  const int ntt = (ntok + T - 1) / T;
  for (int item = wid; item < JBG * ntt; item += NW) {
    const int jg = item % JBG, tt = item / JBG;
    const int j0 = jg * 64 * J2 + lane;
    float acc[J2][T];
#pragma unroll
    for (int u = 0; u < J2; ++u)
#pragma unroll
      for (int t = 0; t < T; ++t) acc[u][t] = 0.f;
    const float* xr = xl + tt * T * xs;
#pragma unroll 4
    for (int k = 0; k < K; k += 4) {
      float4 xv[T];
#pragma unroll
      for (int t = 0; t < T; ++t) xv[t] = *(const float4*)(xr + t * xs + k);
#pragma unroll
      for (int u = 0; u < J2; ++u) {
        float4 w = ld4(Wm + (j0 + u * 64) * K + k);
#pragma unroll
        for (int t = 0; t < T; ++t)
          acc[u][t] += w.x * xv[t].x + w.y * xv[t].y + w.z * xv[t].z + w.w * xv[t].w;
      }
    }
#pragma unroll
    for (int u = 0; u < J2; ++u) {
      float bj = ldw(bias + j0 + u * 64);
#pragma unroll
      for (int t = 0; t < T; ++t) {
        int tok = tt * T + t;
        if (tok < ntok) {
          float v = acc[u][t] + bj;
          if (RELU) v = fmaxf(v, 0.f);
          ol[tok * os + j0 + u * 64] = v;
        }
      }
    }
  }
}

template<int K, typename WT>
__device__ __forceinline__ float dotgf(const WT* __restrict__ w, const float* x){
  float acc = 0.f;
#pragma unroll 8
  for (int k = 0; k < K; k += 4) {
    float4 wv = ld4(w + k);
    acc += wv.x * x[k] + wv.y * x[k+1] + wv.z * x[k+2] + wv.w * x[k+3];
  }
  return acc;
}
template<int K, typename WT>
__device__ __forceinline__ double dotgd(const WT* __restrict__ w, const double* x){
  double acc = 0.0;
#pragma unroll 4
  for (int k = 0; k < K; k += 4) {
    float4 wv = ld4(w + k);
    acc += (double)wv.x * x[k] + (double)wv.y * x[k+1]
         + (double)wv.z * x[k+2] + (double)wv.w * x[k+3];
  }
  return acc;
}
template<int K, typename WT>
__device__ __forceinline__ double dotgdx(const WT* __restrict__ w, const float* x){
  double acc = 0.0;
#pragma unroll 4
  for (int k = 0; k < K; k += 4) {
    float4 wv = ld4(w + k);
    acc += (double)wv.x * (double)x[k] + (double)wv.y * (double)x[k+1]
         + (double)wv.z * (double)x[k+2] + (double)wv.w * (double)x[k+3];
  }
  return acc;
}

template<typename WT>
__device__ void ln_rows(float* xb, const float* ob, const WT* __restrict__ g,
                        const WT* __restrict__ bb, int W, int tid){
  if (tid >= 256) return;
  const int i = tid >> 3, sub = tid & 7;
  const int base = i * XS + sub * 16;
  float y[16];
  float s = 0.f;
#pragma unroll
  for (int u = 0; u < 16; ++u) { y[u] = xb[base + u] + ob[base + u]; s += y[u]; }
  s = wredsum(s, 8);
  const float m = s * (1.0f / 128.0f);
  float vs = 0.f;
#pragma unroll
  for (int u = 0; u < 16; ++u) { float d = y[u] - m; vs += d * d; }
  vs = wredsum(vs, 8);
  const float rstd = 1.0f / sqrtf(vs * (1.0f / 128.0f) + 1e-5f);
  if (i < W) {
#pragma unroll
    for (int u = 0; u < 16; ++u)
      xb[base + u] = (y[u] - m) * rstd * ldw(g + sub * 16 + u) + ldw(bb + sub * 16 + u);
  }
}
template<typename WT>
__device__ __forceinline__ void ln_tail(float* xrow, const float* add,
                                        const WT* __restrict__ g,
                                        const WT* __restrict__ bb, int tid){
  if (tid < 64) {
    float y0 = xrow[tid] + add[tid];
    float y1 = xrow[64 + tid] + add[64 + tid];
    float m = wredsum(y0 + y1, 64) * (1.0f / 128.0f);
    float d0 = y0 - m, d1 = y1 - m;
    float rstd = 1.0f / sqrtf(wredsum(d0 * d0 + d1 * d1, 64) * (1.0f / 128.0f) + 1e-5f);
    xrow[tid] = d0 * rstd * ldw(g + tid) + ldw(bb + tid);
    xrow[64 + tid] = d1 * rstd * ldw(g + 64 + tid) + ldw(bb + 64 + tid);
  }
}

template<typename WT>
__device__ void run_all(const KParams& P, Smem& S, int row, int tid, int isbEmb){
  const WT* pos_emb = (const WT*)P.pos_emb;
  const WT* Wqkv = (const WT*)P.Wqkv;   const WT* bqkv = (const WT*)P.bqkv;
  const WT* Wo = (const WT*)P.Wo;       const WT* bo = (const WT*)P.bo;
  const WT* ln1g = (const WT*)P.ln1g;   const WT* ln1b = (const WT*)P.ln1b;
  const WT* W1 = (const WT*)P.W1;       const WT* b1 = (const WT*)P.b1;
  const WT* W2 = (const WT*)P.W2;       const WT* b2 = (const WT*)P.b2;
  const WT* ln2g = (const WT*)P.ln2g;   const WT* ln2b = (const WT*)P.ln2b;
  const WT* projW = (const WT*)P.projW; const WT* projb = (const WT*)P.projb;
  const WT* gWih = (const WT*)P.gWih;   const WT* gWhh = (const WT*)P.gWhh;
  const WT* gbih = (const WT*)P.gbih;   const WT* gbhh = (const WT*)P.gbhh;
  const WT* accW1 = (const WT*)P.accW1; const WT* accb1 = (const WT*)P.accb1;
  const WT* accW2 = (const WT*)P.accW2; const WT* accb2 = (const WT*)P.accb2;
  const WT* emtW1 = (const WT*)P.emtW1; const WT* emtb1 = (const WT*)P.emtb1;
  const WT* emtW2 = (const WT*)P.emtW2; const WT* emtb2 = (const WT*)P.emtb2;
  const WT* evtW1 = (const WT*)P.evtW1; const WT* evtb1 = (const WT*)P.evtb1;
  const WT* evtW2 = (const WT*)P.evtW2; const WT* evtb2 = (const WT*)P.evtb2;

  if (tid == 0) {
    int seq = 0;
    for (int l = 0; l < 64; ++l) seq += (P.pad[row * 64 + l] == 0);
    S.sI[0] = 0; S.sI[1] = 0; S.sI[2] = (seq == 0) ? 1 : 0; S.sI[3] = seq; S.sI[4] = 0;
  }
  if (tid < 128) S.hsd[tid] = 0.0;
  if (tid < 32) {
    S.win_ids[tid] = 0;
    unsigned a0, a1;
    tfry(0u, 42u, 0u, (unsigned)tid, a0, a1);
    S.keyts[tid][0] = a0; S.keyts[tid][1] = a1;
  }
  __syncthreads();

  for (int t = 0; t < 32; ++t) {
    const int wl = S.sI[0], ip = S.sI[1], done = S.sI[2], seq = S.sI[3];
    const int act = !done;
    const int W = wl;
    const int enc = (act && wl > 0) ? 1 : 0;
    const int jl = (W > 0) ? (W - 1) : 0;

    if (enc) {
      for (int idx = tid; idx < W * 128; idx += 1024) {
        int i = idx >> 7, d = idx & 127;
        S.xbuf[i * XS + d] = temb(P.tok_emb, isbEmb, (long long)S.win_ids[i] * 128 + d)
                             + ldw(pos_emb + i * 128 + d);
      }
      __syncthreads();
      {
        const WT* Wq = Wqkv;
        const WT* bq = bqkv;
        gemm_tok<3, 4, 128, false>(Wq, bq, 384, S.xbuf, XS, S.qh, QS, W, tid);
        __syncthreads();
        if (tid < 128) {
          int h = tid >> 5, i = tid & 31;
          if (i < W) {
            float4 q[8];
#pragma unroll
            for (int kk = 0; kk < 8; ++kk) q[kk] = *(const float4*)&S.qh[i * QS + h * 32 + kk * 4];
            int pb = (h * 32 + i) * PS;
            float m = -1e30f;
            for (int j = 0; j < W; ++j) {
              float s = 0.f;
#pragma unroll
              for (int kk = 0; kk < 8; ++kk)
                s += dot4f(q[kk], *(const float4*)&S.qh[j * QS + 128 + h * 32 + kk * 4]);
              s *= 0.17677669529663687f;
              S.pbuf[pb + j] = s;
              m = fmaxf(m, s);
            }
            float sum = 0.f;
            for (int j = 0; j < W; ++j) { float e = expf(S.pbuf[pb + j] - m); S.pbuf[pb + j] = e; sum += e; }
            float rs = 1.0f / sum;
            for (int j = 0; j < W; ++j) S.pbuf[pb + j] *= rs;
          }
        }
        __syncthreads();
        {
          int c = tid & 127, qsub = tid >> 7, h = c >> 5;
          for (int i = qsub; i < W; i += 8) {
            float acc = 0.f;
            for (int j = 0; j < W; ++j) acc += S.pbuf[(h * 32 + i) * PS + j] * S.qh[j * QS + 256 + c];
            S.obuf[i * XS + c] = acc;
          }
        }
        __syncthreads();
        gemm_tok<1, 4, 128, false>(Wo, bo, 128, S.obuf, XS, S.pbuf, XS, W, tid);
        __syncthreads();
        ln_rows(S.xbuf, S.pbuf, ln1g, ln1b, W, tid);
        __syncthreads();
        gemm_tok<2, 4, 128, true>(W1, b1, 512, S.xbuf, XS, S.qh, HS, W, tid);
        __syncthreads();
        gemm_tok<1, 4, 512, false>(W2, b2, 128, S.qh, HS, S.obuf, XS, W, tid);
        __syncthreads();
        ln_rows(S.xbuf, S.obuf, ln2g, ln2b, W, tid);
        __syncthreads();
      }
      {
        const WT* Wq = Wqkv + 384 * 128;
        const WT* bq = bqkv + 384;
        gemm_tok<1, 4, 128, false>(Wq + 128 * 128, bq + 128, 256, S.xbuf, XS, S.qh + 128, QS, W, tid);
        __syncthreads();
        if (tid < 128)
          S.qh[jl * QS + tid] = ldw(bq + tid) + dotgf<128>(Wq + tid * 128, &S.xbuf[jl * XS]);
        __syncthreads();
        if (tid < 128) {
          int h = tid >> 5, j = tid & 31;
          float s = -1e30f;
          if (j < W) {
            s = 0.f;
#pragma unroll
            for (int kk = 0; kk < 8; ++kk)
              s += dot4f(*(const float4*)&S.qh[jl * QS + h * 32 + kk * 4],
                         *(const float4*)&S.qh[j * QS + 128 + h * 32 + kk * 4]);
            s *= 0.17677669529663687f;
          }
          float m = s;
          for (int mk = 16; mk; mk >>= 1) m = fmaxf(m, __shfl_xor(m, mk, 32));
          float e = (j < W) ? expf(s - m) : 0.f;
          float sum = e;
          for (int mk = 16; mk; mk >>= 1) sum += __shfl_xor(sum, mk, 32);
          if (j < W) S.pbuf[h * PS + j] = e * (1.0f / sum);
        }
        __syncthreads();
        if (tid < 128) {
          int h = tid >> 5;
          float acc = 0.f;
          for (int j = 0; j < W; ++j) acc += S.pbuf[h * PS + j] * S.qh[j * QS + 256 + tid];
          S.attT[tid] = acc;
        }
        __syncthreads();
        if (tid < 128)
          S.tva[tid] = ldw(bo + 128 + tid) + dotgf<128>(Wo + 16384 + tid * 128, S.attT);
        __syncthreads();
        ln_tail(&S.xbuf[jl * XS], S.tva, ln1g + 128, ln1b + 128, tid);
        __syncthreads();
        if (tid < 512)
          S.qh[tid] = fmaxf(ldw(b1 + 512 + tid) + dotgf<128>(W1 + (512 + tid) * 128, &S.xbuf[jl * XS]), 0.f);
        __syncthreads();
        if (tid < 128)
          S.tva[tid] = ldw(b2 + 128 + tid) + dotgf<512>(W2 + (128 + tid) * 512, S.qh);
        __syncthreads();
        ln_tail(&S.xbuf[jl * XS], S.tva, ln2g + 128, ln2b + 128, tid);
        __syncthreads();
      }
    }

    if (tid < 64) {
      double tv = 0.0;
      if (enc) {
        double v = ldwd(projb + tid) + dotgdx<128>(projW + tid * 128, &S.xbuf[jl * XS]);
        double ss = wredsumd(v * v, 64);
        tv = v / fmax(sqrt(ss), 1e-12);
      }
      S.t1d[tid] = tv;
      P.out[(size_t)t * 4096 + row * 64 + tid] = (float)tv;
    }
    __syncthreads();

    if (act) {
      if (tid < 384)
        S.gild[tid] = ldwd(gbih + tid) + dotgd<64>(gWih + tid * 64, S.t1d);
      else if (tid < 768) {
        int j = tid - 384;
        S.ghld[j] = ldwd(gbhh + j) + dotgd<128>(gWhh + j * 128, S.hsd);
      }
      __syncthreads();
      if (tid < 128) {
        double r = 1.0 / (1.0 + exp(-(S.gild[tid] + S.ghld[tid])));
        double z = 1.0 / (1.0 + exp(-(S.gild[128 + tid] + S.ghld[128 + tid])));
        double n = tanh(S.gild[256 + tid] + r * S.ghld[256 + tid]);
        S.hsd[tid] = (1.0 - z) * n + z * S.hsd[tid];
      }
      __syncthreads();
    }

    {
      int ipc = ip < 0 ? 0 : (ip > 63 ? 63 : ip);
      int nt = P.token_ids[row * 64 + ipc];
      int has_in = (act && (ip < seq)) ? 1 : 0;
      if (tid < 320) {
        double v;
        if (tid < 128)      v = has_in ? (double)temb(P.tok_emb, isbEmb, (long long)nt * 128 + tid) : 0.0;
        else if (tid < 192) v = S.t1d[tid - 128];
        else                v = S.hsd[tid - 192];
        S.catd[tid] = v;
      }
    }
    __syncthreads();
    if (tid < 128) {
      S.hid2d[tid] = fmax(ldwd(accb1 + tid) + dotgd<320>(accW1 + tid * 320, S.catd), 0.0);
    } else if (tid < 256) {
      int j = tid - 128;
      S.hid2d[128 + j] = fmax(ldwd(emtb1 + j) + dotgd<192>(emtW1 + j * 192, S.catd + 128), 0.0);
    } else if (tid < 384) {
      int j = tid - 256;
      S.hid2d[256 + j] = fmax(ldwd(evtb1 + j) + dotgd<192>(evtW1 + j * 192, S.catd + 128), 0.0);
    }
    __syncthreads();
    {
      int hw = tid >> 6;
      if (hw < 3) {
        int ln = tid & 63;
        const WT* w2 = (hw == 0) ? accW2 : ((hw == 1) ? emtW2 : evtW2);
        const WT* b2p = (hw == 0) ? accb2 : ((hw == 1) ? emtb2 : evtb2);
        double pp = S.hid2d[hw * 128 + ln] * ldwd(w2 + ln)
                  + S.hid2d[hw * 128 + 64 + ln] * ldwd(w2 + 64 + ln);
        pp = wredsumd(pp, 64);
        if (ln == 0) S.logitsd[hw] = pp + ldwd(b2p);
      }
    }
    __syncthreads();

    if (tid == 0) {
      unsigned k0 = S.keyts[t][0], k1 = S.keyts[t][1];
      unsigned sk[3][2];
      tfry(k0, k1, 0u, 0u, sk[0][0], sk[0][1]);
      tfry(k0, k1, 0u, 1u, sk[1][0], sk[1][1]);
      tfry(k0, k1, 0u, 2u, sk[2][0], sk[2][1]);
      int smp[3];
      double lg[3] = {S.logitsd[0], S.logitsd[1], S.logitsd[2]};
      for (int s = 0; s < 3; ++s) {
        unsigned r0, r1;
        tfry(sk[s][0], sk[s][1], 0u, (unsigned)row, r0, r1);
        unsigned bits = r0 ^ r1;
        double u = (double)u01(bits);
        double p = 1.0 / (1.0 + exp(-lg[s]));
        smp[s] = (u < p) ? 1 : 0;
        P.out[131072 + (size_t)t * 192 + row * 3 + s] = (float)logsigd(smp[s] ? lg[s] : -lg[s]);
        P.out[137216 + (size_t)t * 192 + row * 3 + s] = smp[s] ? 1.0f : 0.0f;
      }
      int wl2 = wl, ip2 = ip, dn = done;
      int nonempty = (wl2 > 0) && act;
      int has_in = act && (ip2 < seq);
      int a = smp[0] && has_in;
      int e = smp[1] && nonempty;
      int v = smp[2] && nonempty;
      int none = act && !(a || e || v);
      a = a || (none && has_in);
      e = e || (none && !has_in && (wl2 > 0));
      int aeff = a && (wl2 < 32);
      int ipc = ip2 < 0 ? 0 : (ip2 > 63 ? 63 : ip2);
      int nt = P.token_ids[row * 64 + ipc];
      if (aeff) { S.win_ids[wl2] = nt; ip2 += 1; wl2 += 1; }
      int emit = e && (wl2 > 0);
      S.sI[4] += emit;
      int veff = v && (wl2 > 0);
      if (veff) {
        int w0 = S.win_ids[0];
#pragma unroll
        for (int i2 = 0; i2 < 31; ++i2) S.win_ids[i2] = S.win_ids[i2 + 1];
        S.win_ids[31] = w0;
        wl2 -= 1;
      }
      if (act && (ip2 >= seq) && (wl2 == 0)) dn = 1;
      S.sI[0] = wl2; S.sI[1] = ip2; S.sI[2] = dn;
    }
    __syncthreads();
  }
  if (tid == 0) P.out[143360 + row] = (float)S.sI[4];
}

__global__ __launch_bounds__(1024) void src_main_kernel(KParams P){
  __shared__ __align__(16) Smem S;
  const int row = blockIdx.x;
  const int tid = threadIdx.x;
  const bool isb = (((const unsigned short*)P.ln1g)[0] == (unsigned short)0x3F80);
  if (isb) run_all<unsigned short>(P, S, row, tid, 1);
  else     run_all<float>(P, S, row, tid, 0);
}

// ======================= launcher =======================
extern "C" void kernel_launch(void* const* d_in, const int* in_sizes, int n_in,
                              void* d_out, int out_size, void* d_ws, size_t ws_size,
                              hipStream_t stream) {
  // entry table: {src d_in idx, srcOff, J, K, trans}
  struct E { int src; int srcOff; int J; int K; int trans; };
  static const E el[35] = {
    {5, 0, 4096, 1, 0},          // 0 pos_emb
    {6, 0, 384, 128, 1},         // 1 WqkvT0
    {6, 49152, 384, 128, 1},     // 2 WqkvT1
    {7, 0, 768, 1, 0},           // 3 bqkv
    {8, 0, 128, 128, 1},         // 4 WoT0
    {8, 16384, 128, 128, 1},     // 5 WoT1
    {9, 0, 256, 1, 0},           // 6 bo
    {10, 0, 256, 1, 0},          // 7 ln1g
    {11, 0, 256, 1, 0},          // 8 ln1b
    {12, 0, 512, 128, 1},        // 9 W1T0
    {12, 65536, 512, 128, 1},    // 10 W1T1
    {13, 0, 1024, 1, 0},         // 11 b1
    {14, 0, 128, 512, 1},        // 12 W2T0
    {14, 65536, 128, 512, 1},    // 13 W2T1
    {15, 0, 256, 1, 0},          // 14 b2
    {16, 0, 256, 1, 0},          // 15 ln2g
    {17, 0, 256, 1, 0},          // 16 ln2b
    {18, 0, 64, 128, 1},         // 17 projWT
    {19, 0, 64, 1, 0},           // 18 projb
    {20, 0, 384, 64, 1},         // 19 gWihT
    {21, 0, 384, 128, 1},        // 20 gWhhT
    {22, 0, 384, 1, 0},          // 21 gbih
    {23, 0, 384, 1, 0},          // 22 gbhh
    {24, 0, 128, 320, 1},        // 23 accW1T
    {25, 0, 128, 1, 0},          // 24 accb1
    {26, 0, 128, 1, 0},          // 25 accW2
    {27, 0, 1, 1, 0},            // 26 accb2
    {28, 0, 128, 192, 1},        // 27 emtW1T
    {29, 0, 128, 1, 0},          // 28 emtb1
    {30, 0, 128, 1, 0},          // 29 emtW2
    {31, 0, 1, 1, 0},            // 30 emtb2
    {32, 0, 128, 192, 1},        // 31 evtW1T
    {33, 0, 128, 1, 0},          // 32 evtb1
    {34, 0, 128, 1, 0},          // 33 evtW2
    {35, 0, 1, 1, 0},            // 34 evtb2
  };
  int offs[35];
  int off = 0;
  for (int i = 0; i < 35; ++i) {
    offs[i] = off;
    off += ((el[i].J * el[i].K) + 3) & ~3;
  }
  size_t need = (size_t)(off + 4) * sizeof(float);

  if (ws_size >= need) {
    float* wsf = (float*)d_ws;
    CvtT C;
    for (int i = 0; i < 35; ++i) {
      C.e[i].src = d_in[el[i].src];
      C.e[i].srcOff = el[i].srcOff;
      C.e[i].J = el[i].J; C.e[i].K = el[i].K;
      C.e[i].trans = el[i].trans;
      C.e[i].off = offs[i];
    }
    C.dst = wsf;
    C.flag = (int*)(wsf + off);
    C.probe = (const unsigned short*)d_in[10];
    hipLaunchKernelGGL(cvt_t_kernel, dim3(256), dim3(256), 0, stream, C);

    TParams P;
    P.token_ids = (const int*)d_in[0];
    P.pad = (const unsigned char*)d_in[1];
    P.tok_emb = d_in[4];
    P.flag = (const int*)(wsf + off);
    P.pos_emb = wsf + offs[0];
    P.WqkvT0 = wsf + offs[1];  P.WqkvT1 = wsf + offs[2];  P.bqkv = wsf + offs[3];
    P.WoT0 = wsf + offs[4];    P.WoT1 = wsf + offs[5];    P.bo = wsf + offs[6];
    P.ln1g = wsf + offs[7];    P.ln1b = wsf + offs[8];
    P.W1T0 = wsf + offs[9];    P.W1T1 = wsf + offs[10];   P.b1 = wsf + offs[11];
    P.W2T0 = wsf + offs[12];   P.W2T1 = wsf + offs[13];   P.b2 = wsf + offs[14];
    P.ln2g = wsf + offs[15];   P.ln2b = wsf + offs[16];
    P.projWT = wsf + offs[17]; P.projb = wsf + offs[18];
    P.gWihT = wsf + offs[19];  P.gWhhT = wsf + offs[20];
    P.gbih = wsf + offs[21];   P.gbhh = wsf + offs[22];
    P.accW1T = wsf + offs[23]; P.accb1 = wsf + offs[24];
    P.accW2 = wsf + offs[25];  P.accb2 = wsf + offs[26];
    P.emtW1T = wsf + offs[27]; P.emtb1 = wsf + offs[28];
    P.emtW2 = wsf + offs[29];  P.emtb2 = wsf + offs[30];
    P.evtW1T = wsf + offs[31]; P.evtb1 = wsf + offs[32];
    P.evtW2 = wsf + offs[33];  P.evtb2 = wsf + offs[34];
    P.out = (float*)d_out;
    hipLaunchKernelGGL(src_main_t, dim3(64), dim3(1024), 0, stream, P);
  } else {
    KParams P;
    P.token_ids = (const int*)d_in[0];
    P.pad = (const unsigned char*)d_in[1];
    P.tok_emb = d_in[4];  P.pos_emb = d_in[5];
    P.Wqkv = d_in[6];     P.bqkv = d_in[7];
    P.Wo = d_in[8];       P.bo = d_in[9];
    P.ln1g = d_in[10];    P.ln1b = d_in[11];
    P.W1 = d_in[12];      P.b1 = d_in[13];
    P.W2 = d_in[14];      P.b2 = d_in[15];
    P.ln2g = d_in[16];    P.ln2b = d_in[17];
    P.projW = d_in[18];   P.projb = d_in[19];
    P.gWih = d_in[20];    P.gWhh = d_in[21];
    P.gbih = d_in[22];    P.gbhh = d_in[23];
    P.accW1 = d_in[24];   P.accb1 = d_in[25];
    P.accW2 = d_in[26];   P.accb2 = d_in[27];
    P.emtW1 = d_in[28];   P.emtb1 = d_in[29];
    P.emtW2 = d_in[30];   P.emtb2 = d_in[31];
    P.evtW1 = d_in[32];   P.evtb1 = d_in[33];
    P.evtW2 = d_in[34];   P.evtb2 = d_in[35];
    P.out = (float*)d_out;
    hipLaunchKernelGGL(src_main_kernel, dim3(64), dim3(1024), 0, stream, P);
  }
}

// Round 7
// 4666.262 us; speedup vs baseline: 1.4707x; 1.4707x over previous
//
#include <hip/hip_runtime.h>
#include <hip/hip_bf16.h>

// ShiftReduceCompressor: persistent kernel, 1 block/row (B=64), 1024 threads,
// 32-iteration scan in-kernel. Encoder fp32, sampling tail fp64, exact
// partitionable JAX threefry. Direct bf16 (or f32) weight reads from d_in
// (1.15 MB footprint, L2-resident), T=8 token-reuse gemms, fused tail.

#define XS 132
#define QS 388
#define HS 516
#define PS 36
#define NW 16

struct KParams {
  const int* token_ids;
  const unsigned char* pad;
  const void *tok_emb, *pos_emb, *Wqkv, *bqkv, *Wo, *bo, *ln1g, *ln1b;
  const void *W1, *b1, *W2, *b2, *ln2g, *ln2b, *projW, *projb;
  const void *gWih, *gWhh, *gbih, *gbhh;
  const void *accW1, *accb1, *accW2, *accb2;
  const void *emtW1, *emtb1, *emtW2, *emtb2;
  const void *evtW1, *evtb1, *evtW2, *evtb2;
  float* out;
};

struct Smem {
  float xbuf[32 * XS];
  float qh[32 * HS];
  float obuf[32 * XS];
  float pbuf[4608];
  float attT[128];
  float tva[128];
  double gild[384];
  double ghld[384];
  double hsd[128];
  double t1d[64];
  double catd[320];
  double hid2d[384];
  double logitsd[3];
  int win_ids[32];
  int sI[6];
  unsigned keyts[32][2];
};

// ---------- typed loads (f32 or bf16) ----------
__device__ __forceinline__ float ldw(const float* p){ return *p; }
__device__ __forceinline__ float ldw(const unsigned short* p){
  return __uint_as_float(((unsigned)*p) << 16);
}
__device__ __forceinline__ float4 ld4(const float* p){ return *(const float4*)p; }
__device__ __forceinline__ float4 ld4(const unsigned short* p){
  ushort4 u = *(const ushort4*)p;
  return make_float4(__uint_as_float((unsigned)u.x << 16),
                     __uint_as_float((unsigned)u.y << 16),
                     __uint_as_float((unsigned)u.z << 16),
                     __uint_as_float((unsigned)u.w << 16));
}
template<typename WT>
__device__ __forceinline__ double ldwd(const WT* p){ return (double)ldw(p); }

__device__ __forceinline__ float temb(const void* te, int isb, long long idx){
  if (isb) return __uint_as_float(((unsigned)((const unsigned short*)te)[idx]) << 16);
  return ((const float*)te)[idx];
}

// ---------- JAX threefry2x32 (partitionable) ----------
__device__ __forceinline__ void tfry(unsigned k0, unsigned k1, unsigned x0, unsigned x1,
                                     unsigned &o0, unsigned &o1){
  unsigned ks2 = k0 ^ k1 ^ 0x1BD11BDAu;
  unsigned x = x0 + k0, y = x1 + k1;
#define TFR(r) { x += y; y = (y << r) | (y >> (32 - r)); y ^= x; }
  TFR(13) TFR(15) TFR(26) TFR(6)  x += k1;  y += ks2 + 1u;
  TFR(17) TFR(29) TFR(16) TFR(24) x += ks2; y += k0 + 2u;
  TFR(13) TFR(15) TFR(26) TFR(6)  x += k0;  y += k1 + 3u;
  TFR(17) TFR(29) TFR(16) TFR(24) x += k1;  y += ks2 + 4u;
  TFR(13) TFR(15) TFR(26) TFR(6)  x += ks2; y += k0 + 5u;
#undef TFR
  o0 = x; o1 = y;
}
__device__ __forceinline__ float u01(unsigned bits){
  return __uint_as_float((bits >> 9) | 0x3f800000u) - 1.0f;
}
__device__ __forceinline__ double logsigd(double x){
  return fmin(x, 0.0) - log1p(exp(-fabs(x)));
}
__device__ __forceinline__ float wredsum(float v, int width){
  for (int m = width >> 1; m > 0; m >>= 1) v += __shfl_xor(v, m, width);
  return v;
}
__device__ __forceinline__ double wredsumd(double v, int width){
  for (int m = width >> 1; m > 0; m >>= 1) v += __shfl_xor(v, m, width);
  return v;
}
__device__ __forceinline__ float dot4f(float4 a, float4 b){
  return a.x*b.x + a.y*b.y + a.z*b.z + a.w*b.w;
}

// out[tok][j] = bias[j] + sum_k W[j][k]*x[tok][k]; lane=j mod 64, J2=1,
// T tokens share one weight fetch. wv/nwv select the participating waves.
template<int T, int K, bool RELU, typename WT>
__device__ void gemm_tok(const WT* __restrict__ Wm, const WT* __restrict__ bias,
                         int J, const float* __restrict__ xl, int xs,
                         float* __restrict__ ol, int os, int ntok,
                         int lane, int wv, int nwv)
{
  const int JBG = J >> 6;
  const int ntt = (ntok + T - 1) / T;
  for (int item = wv; item < JBG * ntt; item += nwv) {
    const int jg = item % JBG, tt = item / JBG;
    const int j0 = jg * 64 + lane;
    float acc[T];
#pragma unroll
    for (int t = 0; t < T; ++t) acc[t] = 0.f;
    const float* xr = xl + tt * T * xs;
    const WT* wr = Wm + j0 * K;
#pragma unroll 4
    for (int k = 0; k < K; k += 4) {
      float4 w = ld4(wr + k);
      float4 xv[T];
#pragma unroll
      for (int t = 0; t < T; ++t) xv[t] = *(const float4*)(xr + t * xs + k);
#pragma unroll
      for (int t = 0; t < T; ++t)
        acc[t] += w.x * xv[t].x + w.y * xv[t].y + w.z * xv[t].z + w.w * xv[t].w;
    }
    float bj = ldw(bias + j0);
#pragma unroll
    for (int t = 0; t < T; ++t) {
      int tok = tt * T + t;
      if (tok < ntok) {
        float v = acc[t] + bj;
        if (RELU) v = fmaxf(v, 0.f);
        ol[tok * os + j0] = v;
      }
    }
  }
}

template<int K, typename WT>
__device__ __forceinline__ float dotgf(const WT* __restrict__ w, const float* x){
  float acc = 0.f;
#pragma unroll 8
  for (int k = 0; k < K; k += 4) {
    float4 wv = ld4(w + k);
    acc += wv.x * x[k] + wv.y * x[k+1] + wv.z * x[k+2] + wv.w * x[k+3];
  }
  return acc;
}
template<int K, typename WT>
__device__ __forceinline__ double dotgd(const WT* __restrict__ w, const double* x){
  double acc = 0.0;
#pragma unroll 4
  for (int k = 0; k < K; k += 4) {
    float4 wv = ld4(w + k);
    acc += (double)wv.x * x[k] + (double)wv.y * x[k+1]
         + (double)wv.z * x[k+2] + (double)wv.w * x[k+3];
  }
  return acc;
}
template<int K, typename WT>
__device__ __forceinline__ double dotgdx(const WT* __restrict__ w, const float* x){
  double acc = 0.0;
#pragma unroll 4
  for (int k = 0; k < K; k += 4) {
    float4 wv = ld4(w + k);
    acc += (double)wv.x * (double)x[k] + (double)wv.y * (double)x[k+1]
         + (double)wv.z * (double)x[k+2] + (double)wv.w * (double)x[k+3];
  }
  return acc;
}

template<typename WT>
__device__ void ln_rows(float* xb, const float* ob, const WT* __restrict__ g,
                        const WT* __restrict__ bb, int W, int tid){
  if (tid >= 256) return;
  const int i = tid >> 3, sub = tid & 7;
  const int base = i * XS + sub * 16;
  float y[16];
  float s = 0.f;
#pragma unroll
  for (int u = 0; u < 16; ++u) { y[u] = xb[base + u] + ob[base + u]; s += y[u]; }
  s = wredsum(s, 8);
  const float m = s * (1.0f / 128.0f);
  float vs = 0.f;
#pragma unroll
  for (int u = 0; u < 16; ++u) { float d = y[u] - m; vs += d * d; }
  vs = wredsum(vs, 8);
  const float rstd = 1.0f / sqrtf(vs * (1.0f / 128.0f) + 1e-5f);
  if (i < W) {
#pragma unroll
    for (int u = 0; u < 16; ++u)
      xb[base + u] = (y[u] - m) * rstd * ldw(g + sub * 16 + u) + ldw(bb + sub * 16 + u);
  }
}
template<typename WT>
__device__ __forceinline__ void ln_tail(float* xrow, const float* add,
                                        const WT* __restrict__ g,
                                        const WT* __restrict__ bb, int tid){
  if (tid < 64) {
    float y0 = xrow[tid] + add[tid];
    float y1 = xrow[64 + tid] + add[64 + tid];
    float m = wredsum(y0 + y1, 64) * (1.0f / 128.0f);
    float d0 = y0 - m, d1 = y1 - m;
    float rstd = 1.0f / sqrtf(wredsum(d0 * d0 + d1 * d1, 64) * (1.0f / 128.0f) + 1e-5f);
    xrow[tid] = d0 * rstd * ldw(g + tid) + ldw(bb + tid);
    xrow[64 + tid] = d1 * rstd * ldw(g + 64 + tid) + ldw(bb + 64 + tid);
  }
}

template<typename WT>
__device__ void run_all(const KParams& P, Smem& S, int row, int tid, int isbEmb){
  const WT* pos_emb = (const WT*)P.pos_emb;
  const WT* Wqkv = (const WT*)P.Wqkv;   const WT* bqkv = (const WT*)P.bqkv;
  const WT* Wo = (const WT*)P.Wo;       const WT* bo = (const WT*)P.bo;
  const WT* ln1g = (const WT*)P.ln1g;   const WT* ln1b = (const WT*)P.ln1b;
  const WT* W1 = (const WT*)P.W1;       const WT* b1 = (const WT*)P.b1;
  const WT* W2 = (const WT*)P.W2;       const WT* b2 = (const WT*)P.b2;
  const WT* ln2g = (const WT*)P.ln2g;   const WT* ln2b = (const WT*)P.ln2b;
  const WT* projW = (const WT*)P.projW; const WT* projb = (const WT*)P.projb;
  const WT* gWih = (const WT*)P.gWih;   const WT* gWhh = (const WT*)P.gWhh;
  const WT* gbih = (const WT*)P.gbih;   const WT* gbhh = (const WT*)P.gbhh;
  const WT* accW1 = (const WT*)P.accW1; const WT* accb1 = (const WT*)P.accb1;
  const WT* accW2 = (const WT*)P.accW2; const WT* accb2 = (const WT*)P.accb2;
  const WT* emtW1 = (const WT*)P.emtW1; const WT* emtb1 = (const WT*)P.emtb1;
  const WT* emtW2 = (const WT*)P.emtW2; const WT* emtb2 = (const WT*)P.emtb2;
  const WT* evtW1 = (const WT*)P.evtW1; const WT* evtb1 = (const WT*)P.evtb1;
  const WT* evtW2 = (const WT*)P.evtW2; const WT* evtb2 = (const WT*)P.evtb2;

  const int lane = tid & 63, wid = tid >> 6;

  if (tid == 0) {
    int seq = 0;
    for (int l = 0; l < 64; ++l) seq += (P.pad[row * 64 + l] == 0);
    S.sI[0] = 0; S.sI[1] = 0; S.sI[2] = (seq == 0) ? 1 : 0; S.sI[3] = seq; S.sI[4] = 0;
  }
  if (tid < 128) S.hsd[tid] = 0.0;
  if (tid < 32) {
    S.win_ids[tid] = 0;
    unsigned a0, a1;
    tfry(0u, 42u, 0u, (unsigned)tid, a0, a1);
    S.keyts[tid][0] = a0; S.keyts[tid][1] = a1;
  }
  __syncthreads();

  for (int t = 0; t < 32; ++t) {
    const int wl = S.sI[0], ip = S.sI[1], done = S.sI[2], seq = S.sI[3];
    const int act = !done;
    const int W = wl;
    const int enc = (act && wl > 0) ? 1 : 0;
    const int jl = (W > 0) ? (W - 1) : 0;

    if (enc) {
      for (int idx = tid; idx < W * 128; idx += 1024) {
        int i = idx >> 7, d = idx & 127;
        S.xbuf[i * XS + d] = temb(P.tok_emb, isbEmb, (long long)S.win_ids[i] * 128 + d)
                             + ldw(pos_emb + i * 128 + d);
      }
      __syncthreads();
      // ---------------- layer 0 (full) ----------------
      gemm_tok<8, 128, false>(Wqkv, bqkv, 384, S.xbuf, XS, S.qh, QS, W, lane, wid, NW);
      __syncthreads();
      if (tid < 128) {
        int h = tid >> 5, i = tid & 31;
        if (i < W) {
          float4 q[8];
#pragma unroll
          for (int kk = 0; kk < 8; ++kk) q[kk] = *(const float4*)&S.qh[i * QS + h * 32 + kk * 4];
          int pb = (h * 32 + i) * PS;
          float m = -1e30f;
          for (int j = 0; j < W; ++j) {
            float s = 0.f;
#pragma unroll
            for (int kk = 0; kk < 8; ++kk)
              s += dot4f(q[kk], *(const float4*)&S.qh[j * QS + 128 + h * 32 + kk * 4]);
            s *= 0.17677669529663687f;
            S.pbuf[pb + j] = s;
            m = fmaxf(m, s);
          }
          float sum = 0.f;
          for (int j = 0; j < W; ++j) { float e = expf(S.pbuf[pb + j] - m); S.pbuf[pb + j] = e; sum += e; }
          float rs = 1.0f / sum;
          for (int j = 0; j < W; ++j) S.pbuf[pb + j] *= rs;
        }
      }
      __syncthreads();
      {
        int c = tid & 127, qsub = tid >> 7, h = c >> 5;
        for (int i = qsub; i < W; i += 8) {
          float acc = 0.f;
          for (int j = 0; j < W; ++j) acc += S.pbuf[(h * 32 + i) * PS + j] * S.qh[j * QS + 256 + c];
          S.obuf[i * XS + c] = acc;
        }
      }
      __syncthreads();
      gemm_tok<4, 128, false>(Wo, bo, 128, S.obuf, XS, S.pbuf, XS, W, lane, wid, NW);
      __syncthreads();
      ln_rows(S.xbuf, S.pbuf, ln1g, ln1b, W, tid);
      __syncthreads();
      gemm_tok<8, 128, true>(W1, b1, 512, S.xbuf, XS, S.qh, HS, W, lane, wid, NW);
      __syncthreads();
      gemm_tok<8, 512, false>(W2, b2, 128, S.qh, HS, S.obuf, XS, W, lane, wid, NW);
      __syncthreads();
      ln_rows(S.xbuf, S.obuf, ln2g, ln2b, W, tid);
      __syncthreads();
      // ---------------- layer 1 (last-token only) ----------------
      {
        const WT* Wq = Wqkv + 384 * 128;
        const WT* bq = bqkv + 384;
        if (wid < 14) {
          gemm_tok<8, 128, false>(Wq + 128 * 128, bq + 128, 256,
                                  S.xbuf, XS, S.qh + 128, QS, W, lane, wid, 14);
        } else {
          int j = tid - 896;  // 0..127
          S.qh[jl * QS + j] = ldw(bq + j) + dotgf<128>(Wq + j * 128, &S.xbuf[jl * XS]);
        }
        __syncthreads();
        if (tid < 128) {
          int h = tid >> 5, j = tid & 31;
          float s = -1e30f;
          if (j < W) {
            s = 0.f;
#pragma unroll
            for (int kk = 0; kk < 8; ++kk)
              s += dot4f(*(const float4*)&S.qh[jl * QS + h * 32 + kk * 4],
                         *(const float4*)&S.qh[j * QS + 128 + h * 32 + kk * 4]);
            s *= 0.17677669529663687f;
          }
          float m = s;
          for (int mk = 16; mk; mk >>= 1) m = fmaxf(m, __shfl_xor(m, mk, 32));
          float e = (j < W) ? expf(s - m) : 0.f;
          float sum = e;
          for (int mk = 16; mk; mk >>= 1) sum += __shfl_xor(sum, mk, 32);
          if (j < W) S.pbuf[h * PS + j] = e * (1.0f / sum);
        }
        __syncthreads();
        if (tid < 128) {
          int h = tid >> 5;
          float acc = 0.f;
          for (int j = 0; j < W; ++j) acc += S.pbuf[h * PS + j] * S.qh[j * QS + 256 + tid];
          S.attT[tid] = acc;
        }
        __syncthreads();
        if (tid < 128)
          S.tva[tid] = ldw(bo + 128 + tid) + dotgf<128>(Wo + 16384 + tid * 128, S.attT);
        __syncthreads();
        ln_tail(&S.xbuf[jl * XS], S.tva, ln1g + 128, ln1b + 128, tid);
        __syncthreads();
        if (tid < 512)
          S.qh[tid] = fmaxf(ldw(b1 + 512 + tid) + dotgf<128>(W1 + (512 + tid) * 128, &S.xbuf[jl * XS]), 0.f);
        __syncthreads();
        if (tid < 128)
          S.tva[tid] = ldw(b2 + 128 + tid) + dotgf<512>(W2 + (128 + tid) * 512, S.qh);
        __syncthreads();
        ln_tail(&S.xbuf[jl * XS], S.tva, ln2g + 128, ln2b + 128, tid);
        __syncthreads();
      }
    }

    // ---- stage A: proj->t1 | ghl | catd-emb ----
    if (tid < 64) {
      double tv = 0.0;
      if (enc) {
        double v = ldwd(projb + tid) + dotgdx<128>(projW + tid * 128, &S.xbuf[jl * XS]);
        double ss = wredsumd(v * v, 64);
        tv = v / fmax(sqrt(ss), 1e-12);
      }
      S.t1d[tid] = tv;
      S.catd[128 + tid] = tv;
      P.out[(size_t)t * 4096 + row * 64 + tid] = (float)tv;
    } else if (tid >= 384 && tid < 768) {
      if (act) {
        int j = tid - 384;
        S.ghld[j] = ldwd(gbhh + j) + dotgd<128>(gWhh + j * 128, S.hsd);
      }
    } else if (tid >= 768 && tid < 896) {
      int j = tid - 768;
      int ipc = ip < 0 ? 0 : (ip > 63 ? 63 : ip);
      int nt = P.token_ids[row * 64 + ipc];
      int has_in = (act && (ip < seq)) ? 1 : 0;
      S.catd[j] = has_in ? (double)temb(P.tok_emb, isbEmb, (long long)nt * 128 + j) : 0.0;
    }
    __syncthreads();

    // ---- stage B: gil (needs t1) ----
    if (act) {
      if (tid < 384)
        S.gild[tid] = ldwd(gbih + tid) + dotgd<64>(gWih + tid * 64, S.t1d);
      __syncthreads();
    }

    // ---- stage C: hsd update + catd-h ----
    if (tid < 128) {
      if (act) {
        double r = 1.0 / (1.0 + exp(-(S.gild[tid] + S.ghld[tid])));
        double z = 1.0 / (1.0 + exp(-(S.gild[128 + tid] + S.ghld[128 + tid])));
        double n = tanh(S.gild[256 + tid] + r * S.ghld[256 + tid]);
        S.hsd[tid] = (1.0 - z) * n + z * S.hsd[tid];
      }
      S.catd[192 + tid] = S.hsd[tid];
    }
    __syncthreads();

    // ---- stage D: three head hidden layers ----
    if (tid < 128) {
      S.hid2d[tid] = fmax(ldwd(accb1 + tid) + dotgd<320>(accW1 + tid * 320, S.catd), 0.0);
    } else if (tid < 256) {
      int j = tid - 128;
      S.hid2d[128 + j] = fmax(ldwd(emtb1 + j) + dotgd<192>(emtW1 + j * 192, S.catd + 128), 0.0);
    } else if (tid < 384) {
      int j = tid - 256;
      S.hid2d[256 + j] = fmax(ldwd(evtb1 + j) + dotgd<192>(evtW1 + j * 192, S.catd + 128), 0.0);
    }
    __syncthreads();

    // ---- stage E: three logits ----
    {
      int hw = tid >> 6;
      if (hw < 3) {
        int ln = tid & 63;
        const WT* w2 = (hw == 0) ? accW2 : ((hw == 1) ? emtW2 : evtW2);
        const WT* b2p = (hw == 0) ? accb2 : ((hw == 1) ? emtb2 : evtb2);
        double pp = S.hid2d[hw * 128 + ln] * ldwd(w2 + ln)
                  + S.hid2d[hw * 128 + 64 + ln] * ldwd(w2 + 64 + ln);
        pp = wredsumd(pp, 64);
        if (ln == 0) S.logitsd[hw] = pp + ldwd(b2p);
      }
    }
    __syncthreads();

    // ---- stage F: sample + state update ----
    if (tid == 0) {
      unsigned k0 = S.keyts[t][0], k1 = S.keyts[t][1];
      unsigned sk[3][2];
      tfry(k0, k1, 0u, 0u, sk[0][0], sk[0][1]);
      tfry(k0, k1, 0u, 1u, sk[1][0], sk[1][1]);
      tfry(k0, k1, 0u, 2u, sk[2][0], sk[2][1]);
      int smp[3];
      double lg[3] = {S.logitsd[0], S.logitsd[1], S.logitsd[2]};
      for (int s = 0; s < 3; ++s) {
        unsigned r0, r1;
        tfry(sk[s][0], sk[s][1], 0u, (unsigned)row, r0, r1);
        unsigned bits = r0 ^ r1;
        double u = (double)u01(bits);
        double p = 1.0 / (1.0 + exp(-lg[s]));
        smp[s] = (u < p) ? 1 : 0;
        P.out[131072 + (size_t)t * 192 + row * 3 + s] = (float)logsigd(smp[s] ? lg[s] : -lg[s]);
        P.out[137216 + (size_t)t * 192 + row * 3 + s] = smp[s] ? 1.0f : 0.0f;
      }
      int wl2 = wl, ip2 = ip, dn = done;
      int nonempty = (wl2 > 0) && act;
      int has_in = act && (ip2 < seq);
      int a = smp[0] && has_in;
      int e = smp[1] && nonempty;
      int v = smp[2] && nonempty;
      int none = act && !(a || e || v);
      a = a || (none && has_in);
      e = e || (none && !has_in && (wl2 > 0));
      int aeff = a && (wl2 < 32);
      int ipc = ip2 < 0 ? 0 : (ip2 > 63 ? 63 : ip2);
      int nt = P.token_ids[row * 64 + ipc];
      if (aeff) { S.win_ids[wl2] = nt; ip2 += 1; wl2 += 1; }
      int emit = e && (wl2 > 0);
      S.sI[4] += emit;
      int veff = v && (wl2 > 0);
      if (veff) {
        int w0 = S.win_ids[0];
#pragma unroll
        for (int i2 = 0; i2 < 31; ++i2) S.win_ids[i2] = S.win_ids[i2 + 1];
        S.win_ids[31] = w0;
        wl2 -= 1;
      }
      if (act && (ip2 >= seq) && (wl2 == 0)) dn = 1;
      S.sI[0] = wl2; S.sI[1] = ip2; S.sI[2] = dn;
    }
    __syncthreads();
  }
  if (tid == 0) P.out[143360 + row] = (float)S.sI[4];
}

__global__ __launch_bounds__(1024) void src_main_kernel(KParams P){
  __shared__ __align__(16) Smem S;
  const int row = blockIdx.x;
  const int tid = threadIdx.x;
  const bool isb = (((const unsigned short*)P.ln1g)[0] == (unsigned short)0x3F80);
  if (isb) run_all<unsigned short>(P, S, row, tid, 1);
  else     run_all<float>(P, S, row, tid, 0);
}

extern "C" void kernel_launch(void* const* d_in, const int* in_sizes, int n_in,
                              void* d_out, int out_size, void* d_ws, size_t ws_size,
                              hipStream_t stream) {
  KParams P;
  P.token_ids = (const int*)d_in[0];
  P.pad = (const unsigned char*)d_in[1];
  P.tok_emb = d_in[4];  P.pos_emb = d_in[5];
  P.Wqkv = d_in[6];     P.bqkv = d_in[7];
  P.Wo = d_in[8];       P.bo = d_in[9];
  P.ln1g = d_in[10];    P.ln1b = d_in[11];
  P.W1 = d_in[12];      P.b1 = d_in[13];
  P.W2 = d_in[14];      P.b2 = d_in[15];
  P.ln2g = d_in[16];    P.ln2b = d_in[17];
  P.projW = d_in[18];   P.projb = d_in[19];
  P.gWih = d_in[20];    P.gWhh = d_in[21];
  P.gbih = d_in[22];    P.gbhh = d_in[23];
  P.accW1 = d_in[24];   P.accb1 = d_in[25];
  P.accW2 = d_in[26];   P.accb2 = d_in[27];
  P.emtW1 = d_in[28];   P.emtb1 = d_in[29];
  P.emtW2 = d_in[30];   P.emtb2 = d_in[31];
  P.evtW1 = d_in[32];   P.evtb1 = d_in[33];
  P.evtW2 = d_in[34];   P.evtb2 = d_in[35];
  P.out = (float*)d_out;
  hipLaunchKernelGGL(src_main_kernel, dim3(64), dim3(1024), 0, stream, P);
}